// Round 2
// baseline (498.443 us; speedup 1.0000x reference)
//
#include <hip/hip_runtime.h>

typedef unsigned int u32;

#define HD 256
#define VD 8192
#define SD 4096
#define H2 512

// ws float offsets
#define WS_CI    384    // 512
#define WS_G     896    // 768
#define WS_PMAX  1664   // 128 (per-block logit maxima from k6)
#define WS_HN    2432   // 256
#define WS_EIJ   2688   // 4096

__device__ __forceinline__ float dot4(float4 a, float4 b, float acc) {
    acc = fmaf(a.x, b.x, acc); acc = fmaf(a.y, b.y, acc);
    acc = fmaf(a.z, b.z, acc); return fmaf(a.w, b.w, acc);
}
__device__ __forceinline__ float wred64(float v) {
    #pragma unroll
    for (int o = 32; o; o >>= 1) v += __shfl_xor(v, o);
    return v;
}

// KA: blocks 0..255 -> attention scores (k1, with block-local wa_h);
//     blocks 256..447 -> gate U/W matvecs (wave-per-row); block 256 zeroes Ci.
__global__ __launch_bounds__(256) void ka_front(const int* __restrict__ tok,
        const float* __restrict__ emb,
        const float* __restrict__ Uz_w, const float* __restrict__ Uz_b,
        const float* __restrict__ Wz_w, const float* __restrict__ Wz_b,
        const float* __restrict__ Ur_w, const float* __restrict__ Ur_b,
        const float* __restrict__ Wr_w, const float* __restrict__ Wr_b,
        const float* __restrict__ Uh_w, const float* __restrict__ Uh_b,
        const float* __restrict__ Wa_w, const float* __restrict__ Wa_b,
        const float* __restrict__ Ua_w, const float* __restrict__ Ua_b,
        const float* __restrict__ Va_w, const float* __restrict__ Va_b,
        const float* __restrict__ enc, const float* __restrict__ hidden,
        float* __restrict__ G, float* __restrict__ Eij, float* __restrict__ Ci) {
    int t = threadIdx.x, lane = t & 63, wv = t >> 6;

    if (blockIdx.x >= 256) {
        // ---- gate rows: wg in 0..767, g = gate (z,r,h), i = row ----
        int bb = blockIdx.x - 256;
        if (bb == 0) { Ci[t] = 0.f; Ci[t + 256] = 0.f; }
        int wg = bb * 4 + wv;
        int g = wg >> 8, i = wg & 255;
        const float* U = (g == 0 ? Uz_w : (g == 1 ? Ur_w : Uh_w)) + (size_t)i * VD;
        const float* y = emb + (size_t)tok[0] * VD;
        float acc = 0.f;
        for (int c = 0; c < VD; c += 512) {
            int k = c + lane * 8;
            acc = dot4(*(const float4*)(U + k),     *(const float4*)(y + k),     acc);
            acc = dot4(*(const float4*)(U + k + 4), *(const float4*)(y + k + 4), acc);
        }
        if (g < 2) {
            const float* W = (g == 0 ? Wz_w : Wr_w) + (size_t)i * HD;
            int k = lane * 4;
            acc = dot4(*(const float4*)(W + k), *(const float4*)(hidden + k), acc);
        }
        acc = wred64(acc);
        if (lane == 0) {
            float b;
            if (g == 0)      b = Uz_b[i] + Wz_b[i];
            else if (g == 1) b = Ur_b[i] + Wr_b[i];
            else             b = Uh_b[i];
            G[wg] = acc + b;
        }
        return;
    }

    // ---- k1: Eij[s] = Va . tanh(Wa@h + Wa_b + Ua_b + Ua_w @ enc[s]), 16 rows/block ----
    __shared__ __align__(16) float encs[16 * H2];   // 32 KB
    __shared__ __align__(16) float hs[HD];
    __shared__ float wah[HD];
    int sg = wv;
    int h0 = lane * 4;
    long s0 = (long)blockIdx.x * 16;

    for (int i = t * 4; i < 16 * H2; i += 1024)
        *(float4*)&encs[i] = *(const float4*)(enc + s0 * H2 + i);
    hs[t] = hidden[t];
    __syncthreads();

    // block-local wa_h (thread-per-row), with Wa_b + Ua_b folded in
    {
        float wacc = 0.f;
        const float4* wrow = (const float4*)(Wa_w + (size_t)t * HD);
        #pragma unroll 4
        for (int k = 0; k < HD / 4; ++k)
            wacc = dot4(wrow[k], *(const float4*)&hs[k * 4], wacc);
        wah[t] = wacc + Wa_b[t] + Ua_b[t];
    }
    __syncthreads();

    float acc[4][4];
    #pragma unroll
    for (int a = 0; a < 4; ++a)
        #pragma unroll
        for (int b = 0; b < 4; ++b) acc[a][b] = 0.f;

    const float* r0 = Ua_w + (size_t)(h0 + 0) * H2;
    const float* r1 = Ua_w + (size_t)(h0 + 1) * H2;
    const float* r2 = Ua_w + (size_t)(h0 + 2) * H2;
    const float* r3 = Ua_w + (size_t)(h0 + 3) * H2;
    for (int kc = 0; kc < H2; kc += 4) {
        float4 a0 = *(const float4*)(r0 + kc);
        float4 a1 = *(const float4*)(r1 + kc);
        float4 a2 = *(const float4*)(r2 + kc);
        float4 a3 = *(const float4*)(r3 + kc);
        #pragma unroll
        for (int ss = 0; ss < 4; ++ss) {
            float4 ev = *(const float4*)&encs[(sg * 4 + ss) * H2 + kc];
            acc[ss][0] = dot4(a0, ev, acc[ss][0]);
            acc[ss][1] = dot4(a1, ev, acc[ss][1]);
            acc[ss][2] = dot4(a2, ev, acc[ss][2]);
            acc[ss][3] = dot4(a3, ev, acc[ss][3]);
        }
    }

    float bias[4], va[4];
    #pragma unroll
    for (int j = 0; j < 4; ++j) {
        bias[j] = wah[h0 + j];
        va[j]   = Va_w[h0 + j];
    }
    float vb = Va_b[0];
    #pragma unroll
    for (int ss = 0; ss < 4; ++ss) {
        float v = 0.f;
        #pragma unroll
        for (int j = 0; j < 4; ++j)
            v += va[j] * tanhf(acc[ss][j] + bias[j]);
        v = wred64(v);
        if (lane == 0) Eij[s0 + sg * 4 + ss] = v + vb;
    }
}

// KB: softmax stats (redundant per block, Eij is L2-hot) + aij -> out + Ci += sum aij*enc
__global__ __launch_bounds__(256) void kb_ci(const float* __restrict__ Eij,
                                             const float* __restrict__ enc,
                                             float* __restrict__ out,
                                             float* __restrict__ Ci) {
    __shared__ float sm[4];
    __shared__ float a[64];
    int t = threadIdx.x, lane = t & 63, wv = t >> 6;

    float m = -1e30f;
    for (int i = t; i < SD; i += 256) m = fmaxf(m, Eij[i]);
    #pragma unroll
    for (int o = 32; o; o >>= 1) m = fmaxf(m, __shfl_xor(m, o));
    if (lane == 0) sm[wv] = m;
    __syncthreads();
    m = fmaxf(fmaxf(sm[0], sm[1]), fmaxf(sm[2], sm[3]));
    __syncthreads();
    float s = 0.f;
    for (int i = t; i < SD; i += 256) s += __expf(Eij[i] - m);
    s = wred64(s);
    if (lane == 0) sm[wv] = s;
    __syncthreads();
    s = sm[0] + sm[1] + sm[2] + sm[3];
    float rinv = 1.f / s;

    long s0 = (long)blockIdx.x * 64;
    if (t < 64) {
        float v = __expf(Eij[s0 + t] - m) * rinv;
        a[t] = v;
        out[8448 + s0 + t] = v;
    }
    __syncthreads();
    float acc0 = 0.f, acc1 = 0.f;
    for (int ss = 0; ss < 64; ++ss) {
        float av = a[ss];
        const float* r = enc + (s0 + ss) * H2;
        acc0 = fmaf(av, r[t], acc0);
        acc1 = fmaf(av, r[t + 256], acc1);
    }
    atomicAdd(Ci + t, acc0);
    atomicAdd(Ci + t + 256, acc1);
}

// KC: fused k5a+k5c. Phase 1: thread-per-row r-gate (ar) -> rh in LDS.
//     Phase 2: wave-per-row z / pre-c / Wh.(r*h) dots -> hn.
__global__ __launch_bounds__(256) void kc_hnew(const float* __restrict__ G,
        const float* __restrict__ Ci,
        const float* __restrict__ Cz_w, const float* __restrict__ Cz_b,
        const float* __restrict__ Cr_w, const float* __restrict__ Cr_b,
        const float* __restrict__ Ch_w, const float* __restrict__ Ch_b,
        const float* __restrict__ Wh_w, const float* __restrict__ Wh_b,
        const float* __restrict__ hidden,
        float* __restrict__ hn_f, float* __restrict__ out) {
    __shared__ __align__(16) float cis[H2];
    __shared__ __align__(16) float rh[HD];
    int t = threadIdx.x, lane = t & 63, wv = t >> 6;

    if (t < 128) *(float4*)&cis[t * 4] = *(const float4*)(Ci + t * 4);
    __syncthreads();

    // phase 1: ar[t] = G[256+t] + Cr[t,:].Ci + Cr_b[t];  rh[t] = h[t]*sigmoid(ar)
    {
        float acc = 0.f;
        const float4* cr = (const float4*)(Cr_w + (size_t)t * H2);
        #pragma unroll 4
        for (int k = 0; k < H2 / 4; ++k)
            acc = dot4(cr[k], *(const float4*)&cis[k * 4], acc);
        float arv = G[256 + t] + acc + Cr_b[t];
        rh[t] = hidden[t] / (1.f + __expf(-arv));
    }
    __syncthreads();

    // phase 2: wave wv handles output row i
    int i = blockIdx.x * 4 + wv;
    int k8 = lane * 8;
    const float* Cz = Cz_w + (size_t)i * H2;
    const float* Ch = Ch_w + (size_t)i * H2;
    float az = dot4(*(const float4*)(Cz + k8),     *(const float4*)&cis[k8],     0.f);
    az       = dot4(*(const float4*)(Cz + k8 + 4), *(const float4*)&cis[k8 + 4], az);
    float ah = dot4(*(const float4*)(Ch + k8),     *(const float4*)&cis[k8],     0.f);
    ah       = dot4(*(const float4*)(Ch + k8 + 4), *(const float4*)&cis[k8 + 4], ah);
    float aw = dot4(*(const float4*)(Wh_w + (size_t)i * HD + lane * 4),
                    *(const float4*)&rh[lane * 4], 0.f);
    az = wred64(az); ah = wred64(ah); aw = wred64(aw);
    if (lane == 0) {
        float z  = 1.f / (1.f + __expf(-(G[i] + az + Cz_b[i])));
        float pc = G[512 + i] + ah + Ch_b[i] + Wh_b[i];
        float c  = tanhf(pc + aw);
        float hnv = (1.f - z) * c + z * hidden[i];
        hn_f[i] = hnv;
        out[8192 + i] = hnv;
    }
}

// K6: logits -> out[0..8191] (wave-per-row, 16 rows/wave) + per-block max -> pmax
__global__ __launch_bounds__(256) void k6_logits(const float* __restrict__ Vw,
        const float* __restrict__ Vb, const float* __restrict__ hn,
        float* __restrict__ out, float* __restrict__ pmax) {
    __shared__ float bm[4];
    int t = threadIdx.x, lane = t & 63, wv = t >> 6;
    float4 h4 = *(const float4*)(hn + lane * 4);
    long r0 = ((long)blockIdx.x * 4 + wv) * 16;
    float pm = -1e30f;
    for (int rr = 0; rr < 16; ++rr) {
        long j = r0 + rr;
        float acc = dot4(*(const float4*)(Vw + j * HD + lane * 4), h4, 0.f);
        acc = wred64(acc);
        float lg = acc + Vb[j];
        if (lane == 0) out[j] = lg;
        pm = fmaxf(pm, lg);
    }
    if (lane == 0) bm[wv] = pm;
    __syncthreads();
    if (t == 0) pmax[blockIdx.x] = fmaxf(fmaxf(bm[0], bm[1]), fmaxf(bm[2], bm[3]));
}

// K7: in-place log_softmax over out[0..8191], using per-block maxima
__global__ __launch_bounds__(256) void k7_lsm(float* __restrict__ out,
                                              const float* __restrict__ pmax) {
    __shared__ float sh[4];
    int t = threadIdx.x, lane = t & 63, wv = t >> 6;
    float m = (t < 128) ? pmax[t] : -1e30f;
    #pragma unroll
    for (int o = 32; o; o >>= 1) m = fmaxf(m, __shfl_xor(m, o));
    if (lane == 0) sh[wv] = m;
    __syncthreads();
    m = fmaxf(fmaxf(sh[0], sh[1]), fmaxf(sh[2], sh[3]));
    __syncthreads();
    float s = 0.f;
    for (int i = t; i < VD; i += 256) s += __expf(out[i] - m);
    s = wred64(s);
    if (lane == 0) sh[wv] = s;
    __syncthreads();
    s = sh[0] + sh[1] + sh[2] + sh[3];
    float lse = m + __logf(s);
    for (int i = t; i < VD; i += 256) out[i] = out[i] - lse;
}

extern "C" void kernel_launch(void* const* d_in, const int* in_sizes, int n_in,
                              void* d_out, int out_size, void* d_ws, size_t ws_size,
                              hipStream_t stream) {
    const int*   tok    = (const int*)d_in[0];
    const float* hidden = (const float*)d_in[1];
    const float* enc    = (const float*)d_in[2];
    const float* emb    = (const float*)d_in[3];
    const float* Uz_w = (const float*)d_in[4],  *Uz_b = (const float*)d_in[5];
    const float* Wz_w = (const float*)d_in[6],  *Wz_b = (const float*)d_in[7];
    const float* Cz_w = (const float*)d_in[8],  *Cz_b = (const float*)d_in[9];
    const float* Ur_w = (const float*)d_in[10], *Ur_b = (const float*)d_in[11];
    const float* Wr_w = (const float*)d_in[12], *Wr_b = (const float*)d_in[13];
    const float* Cr_w = (const float*)d_in[14], *Cr_b = (const float*)d_in[15];
    const float* Uh_w = (const float*)d_in[16], *Uh_b = (const float*)d_in[17];
    const float* Wh_w = (const float*)d_in[18], *Wh_b = (const float*)d_in[19];
    const float* Ch_w = (const float*)d_in[20], *Ch_b = (const float*)d_in[21];
    const float* Ua_w = (const float*)d_in[22], *Ua_b = (const float*)d_in[23];
    const float* Wa_w = (const float*)d_in[24], *Wa_b = (const float*)d_in[25];
    const float* Va_w = (const float*)d_in[26], *Va_b = (const float*)d_in[27];
    const float* V_w  = (const float*)d_in[28], *V_b  = (const float*)d_in[29];

    float* ws    = (float*)d_ws;
    float* Ci    = ws + WS_CI;
    float* G     = ws + WS_G;
    float* pmax  = ws + WS_PMAX;
    float* hn_f  = ws + WS_HN;
    float* Eij   = ws + WS_EIJ;
    float* out   = (float*)d_out;

    ka_front<<<448, 256, 0, stream>>>(tok, emb, Uz_w, Uz_b, Wz_w, Wz_b,
                                      Ur_w, Ur_b, Wr_w, Wr_b, Uh_w, Uh_b,
                                      Wa_w, Wa_b, Ua_w, Ua_b, Va_w, Va_b,
                                      enc, hidden, G, Eij, Ci);
    kb_ci<<<64, 256, 0, stream>>>(Eij, enc, out, Ci);
    kc_hnew<<<64, 256, 0, stream>>>(G, Ci, Cz_w, Cz_b, Cr_w, Cr_b,
                                    Ch_w, Ch_b, Wh_w, Wh_b, hidden, hn_f, out);
    k6_logits<<<128, 256, 0, stream>>>(V_w, V_b, hn_f, out, pmax);
    k7_lsm<<<1, 256, 0, stream>>>(out, pmax);
}